// Round 8
// baseline (233.773 us; speedup 1.0000x reference)
//
#include <hip/hip_runtime.h>

#define DD 256
#define KK 8192
#define HW 1024
#define NROWS 16384
#define NELEM 4194304
#define MT 32            // rerank row-tile (loss-order preserving: DO NOT CHANGE)
#define MS 64            // screen row-tile
#define MARGIN 6e-4f     // bf16-screen deterministic bound (r0-r4 verified)
#define WCAP 1024

typedef __attribute__((ext_vector_type(8))) short short8;
typedef __attribute__((ext_vector_type(4))) float f32x4;
typedef unsigned short ushort;
typedef unsigned int uint;
typedef unsigned long long u64;

// ---- exact replication of numpy pairwise_sum (n=256) over squares ----
__device__ __forceinline__ float np_pw128_sq(const float* p) {
  float r[8];
#pragma unroll
  for (int j = 0; j < 8; ++j) r[j] = __fmul_rn(p[j], p[j]);
  for (int i = 8; i < 128; i += 8) {
#pragma unroll
    for (int j = 0; j < 8; ++j)
      r[j] = __fadd_rn(r[j], __fmul_rn(p[i + j], p[i + j]));
  }
  return __fadd_rn(__fadd_rn(__fadd_rn(r[0], r[1]), __fadd_rn(r[2], r[3])),
                   __fadd_rn(__fadd_rn(r[4], r[5]), __fadd_rn(r[6], r[7])));
}

__device__ __forceinline__ ushort f2bf(float x) {   // RNE float->bf16 bits
  uint u = __float_as_uint(x);
  u += 0x7FFF + ((u >> 16) & 1);
  return (ushort)(u >> 16);
}

// order-preserving float<->uint (screened minima are NEGATIVE - r5 lesson)
__device__ __forceinline__ uint fenc(float f) {
  uint u = __float_as_uint(f);
  return (u & 0x80000000u) ? ~u : (u | 0x80000000u);
}
__device__ __forceinline__ float fdec(uint k) {
  return __uint_as_float((k & 0x80000000u) ? (k & 0x7FFFFFFFu) : ~k);
}

// running top-2 (min, argmin, min2) helpers for the screen
struct Top2 { float m1, m2; int i1; };

__device__ __forceinline__ void top2_upd(Top2& s, const f32x4 a,
                                         const f32x4 Bs, int ibase) {
  float d0 = fmaf(-2.f, a[0], Bs[0]);
  float d1 = fmaf(-2.f, a[1], Bs[1]);
  float d2 = fmaf(-2.f, a[2], Bs[2]);
  float d3 = fmaf(-2.f, a[3], Bs[3]);
  float lo01 = fminf(d0, d1), hi01 = fmaxf(d0, d1);
  int io01 = d1 < d0 ? ibase + 1 : ibase;
  float lo23 = fminf(d2, d3), hi23 = fmaxf(d2, d3);
  int io23 = d3 < d2 ? ibase + 3 : ibase + 2;
  float n1 = fminf(lo01, lo23);
  int ni = lo23 < lo01 ? io23 : io01;
  float n2 = fminf(fmaxf(lo01, lo23), fminf(hi01, hi23));
  s.m2 = fminf(fmaxf(s.m1, n1), fminf(s.m2, n2));   // uses OLD m1
  s.i1 = n1 < s.m1 ? ni : s.i1;
  s.m1 = fminf(s.m1, n1);
}

__device__ __forceinline__ void top2_bfly(Top2& s, int off) {
  float om1 = __shfl_xor(s.m1, off);
  int oi1 = __shfl_xor(s.i1, off);
  float om2 = __shfl_xor(s.m2, off);
  s.m2 = fminf(fmaxf(s.m1, om1), fminf(s.m2, om2));
  s.i1 = om1 < s.m1 ? oi1 : s.i1;   // ties keep own; covered by m2<=thr path
  s.m1 = fminf(s.m1, om1);
}

__device__ __forceinline__ uint pack_m2(float m2, int i1) {
  // bf16 rounded toward -inf (conservative: never hides a full-scan), idx in low bits
  uint u = __float_as_uint(m2);
  uint hi = u & 0xFFFF0000u;
  if ((u & 0x80000000u) && (u & 0xFFFFu)) hi += 0x10000u;
  return hi | (uint)i1;
}

// ======== prep: Bk | cbB bf16 fragments (r4-verified) ========
__global__ __launch_bounds__(256) void vq_prep(const float* __restrict__ cb,
                                               float* __restrict__ Bk,
                                               ushort* __restrict__ cbB) {
  const int b = blockIdx.x, t = threadIdx.x;
  if (b < 32) {                // ||e_k||^2, numpy-exact
    int k = b * 256 + t;
    const float* p = cb + (size_t)k * DD;
    Bk[k] = __fadd_rn(np_pw128_sq(p), np_pw128_sq(p + 128));
  } else {                     // cbB fragments (layout verified r7/r8/r9)
    int tid = (b - 32) * 256 + t;
    int g = tid >> 9, s = (tid >> 6) & 7, lane = tid & 63;
    int code = g * 16 + (lane & 15);
    int dbase = s * 32 + (lane >> 4) * 8;
    const float* p = cb + (size_t)code * DD + dbase;
    ushort bb[8];
#pragma unroll
    for (int j = 0; j < 8; ++j) bb[j] = f2bf(p[j]);
    uint4 pk;
    pk.x = bb[0] | ((uint)bb[1] << 16);
    pk.y = bb[2] | ((uint)bb[3] << 16);
    pk.z = bb[4] | ((uint)bb[5] << 16);
    pk.w = bb[6] | ((uint)bb[7] << 16);
    *(uint4*)(cbB + (size_t)tid * 8) = pk;
  }
}

// ======== screen: bf16 MFMA, 64 rows/block, per-tile32 top-2 ========
// KEY FIX vs r7: slice->XCD binding is now RUNTIME-GUARANTEED, not assumed.
// Every round since r1 assumed bid%4 -> XCD round-robin; the ISA guide says
// workgroup->XCD assignment is UNDEFINED. If that assumption is wrong, each
// XCD streams all 4.2 MB of cbB through its 4 MB L2 -> every gg misses to
// L3 (~600-900 cyc) -> the structure-invariant ~95 us wall (1.7k cyc/gg vs
// ~500 compute). Now each block reads HW_REG_XCC_ID (m09-verified) and
// CLAIMS a (rt, cs) pair with preferred cs = xcc&3 via counters + work-
// stealing (pigeonhole: 1024 blocks / 1024 slots, <=1 valid claim each ->
// every block finds a slot in one 4-slice scan). Dispatch-independent
// correctness; bit-identical outputs (same tiles computed, by whoever).
#define GG_BODY(BUF, GGI, IB)                                                  \
  {                                                                            \
    f32x4 A0 = {0,0,0,0}, A1 = {0,0,0,0}, A2 = {0,0,0,0}, A3 = {0,0,0,0};      \
    _Pragma("unroll")                                                          \
    for (int s = 0; s < 8; ++s) {                                              \
      A0 = __builtin_amdgcn_mfma_f32_16x16x32_bf16(BUF[s], aF0[s], A0, 0, 0, 0);\
      A1 = __builtin_amdgcn_mfma_f32_16x16x32_bf16(BUF[s], aF1[s], A1, 0, 0, 0);\
      A2 = __builtin_amdgcn_mfma_f32_16x16x32_bf16(BUF[s], aF2[s], A2, 0, 0, 0);\
      A3 = __builtin_amdgcn_mfma_f32_16x16x32_bf16(BUF[s], aF3[s], A3, 0, 0, 0);\
    }                                                                          \
    const f32x4 Bs = *(const f32x4*)(BkS + (GGI) * 16 - cbase + quad * 4);     \
    top2_upd(c0, A0, Bs, IB); top2_upd(c1, A1, Bs, IB);                        \
    top2_upd(c2, A2, Bs, IB); top2_upd(c3, A3, Bs, IB);                        \
  }

__global__ __launch_bounds__(256) void vq_screen(
    const float* __restrict__ z, const ushort* __restrict__ cbB,
    const float* __restrict__ Bk, float* __restrict__ tA,
    uint* __restrict__ tB, uint* __restrict__ rowMinG,
    int* __restrict__ ctr) {
  __shared__ ushort ztB[MS][264];   // 33 KB; 264 keeps 16B row alignment
  __shared__ float BkS[2048];       // this block's code-slice norms (8 KB)
  __shared__ int claim[2];
  const int t = threadIdx.x;

  if (t == 0) {                     // claim (rt, cs); prefer this XCD's slice
    uint xcc;
    asm volatile("s_getreg_b32 %0, hwreg(HW_REG_XCC_ID)" : "=s"(xcc));
    const int cs0 = (int)(xcc & 3u);
    int rt = 0, cs = 0;
#pragma unroll
    for (int i = 0; i < 4; ++i) {
      const int c = (cs0 + i) & 3;
      const int v = atomicAdd(&ctr[c], 1);
      if (v < NROWS / MS) { rt = v; cs = c; break; }
    }
    claim[0] = rt; claim[1] = cs;
  }
  __syncthreads();
  const int rt = claim[0], cs = claim[1];

  const int n0 = rt * MS;
  const int bimg = n0 >> 10, hw0 = n0 & 1023;
  const float* zb = z + (size_t)bimg * DD * HW + hw0;

  for (int li = t; li < MS * 128; li += 256) {   // 64 rows x 128 d-pairs
    int r = li & 63, dp = li >> 6;
    float v0 = zb[(size_t)(2 * dp) * HW + r];
    float v1 = zb[(size_t)(2 * dp + 1) * HW + r];
    *(uint*)&ztB[r][2 * dp] = (uint)f2bf(v0) | ((uint)f2bf(v1) << 16);
  }
  for (int li = t; li < 2048; li += 256) BkS[li] = Bk[cs * 2048 + li];
  __syncthreads();

  const int w = t >> 6, lane = t & 63;
  const int quad = lane >> 4, n16 = lane & 15;

  short8 aF0[8], aF1[8], aF2[8], aF3[8];   // z fragments, 4 row-groups
#pragma unroll
  for (int s = 0; s < 8; ++s) {
    aF0[s] = *(const short8*)&ztB[n16][s * 32 + quad * 8];
    aF1[s] = *(const short8*)&ztB[16 + n16][s * 32 + quad * 8];
    aF2[s] = *(const short8*)&ztB[32 + n16][s * 32 + quad * 8];
    aF3[s] = *(const short8*)&ztB[48 + n16][s * 32 + quad * 8];
  }

  const int gg0 = cs * 128 + w * 32;   // 32 16-code groups = 16 tiles per wave
  const int cbase = cs * 2048;
  Top2 c0 = {3.4e38f, 3.4e38f, 0}, c1 = {3.4e38f, 3.4e38f, 0};
  Top2 c2 = {3.4e38f, 3.4e38f, 0}, c3 = {3.4e38f, 3.4e38f, 0};
  float rmin = 3.4e38f;

  short8 b0[8], b1[8];
  {
    const ushort* bp = cbB + (size_t)gg0 * 4096 + lane * 8;
#pragma unroll
    for (int s = 0; s < 8; ++s) b0[s] = *(const short8*)(bp + s * 512);
  }

  for (int gp = 0; gp < 16; ++gp) {     // ping-pong pairs; tile = gg pair
    const int gg = gg0 + gp * 2;
    {
      const ushort* bp = cbB + (size_t)(gg + 1) * 4096 + lane * 8;
#pragma unroll
      for (int s = 0; s < 8; ++s) b1[s] = *(const short8*)(bp + s * 512);
    }
    GG_BODY(b0, gg, quad * 4)
    if (gp < 15) {
      const ushort* bp = cbB + (size_t)(gg + 2) * 4096 + lane * 8;
#pragma unroll
      for (int s = 0; s < 8; ++s) b0[s] = *(const short8*)(bp + s * 512);
    }
    GG_BODY(b1, gg + 1, 16 + quad * 4)
    // tile complete: merge quads, NT-store, track row-min, reset
    top2_bfly(c0, 16); top2_bfly(c0, 32);
    top2_bfly(c1, 16); top2_bfly(c1, 32);
    top2_bfly(c2, 16); top2_bfly(c2, 32);
    top2_bfly(c3, 16); top2_bfly(c3, 32);
    const size_t tbase = (size_t)(gg >> 1) * NROWS + n0;
    if (quad == 0) {
      __builtin_nontemporal_store(c0.m1, &tA[tbase + n16]);
      __builtin_nontemporal_store(pack_m2(c0.m2, c0.i1), &tB[tbase + n16]);
      rmin = fminf(rmin, c0.m1);
    } else if (quad == 1) {
      __builtin_nontemporal_store(c1.m1, &tA[tbase + 16 + n16]);
      __builtin_nontemporal_store(pack_m2(c1.m2, c1.i1), &tB[tbase + 16 + n16]);
      rmin = fminf(rmin, c1.m1);
    } else if (quad == 2) {
      __builtin_nontemporal_store(c2.m1, &tA[tbase + 32 + n16]);
      __builtin_nontemporal_store(pack_m2(c2.m2, c2.i1), &tB[tbase + 32 + n16]);
      rmin = fminf(rmin, c2.m1);
    } else {
      __builtin_nontemporal_store(c3.m1, &tA[tbase + 48 + n16]);
      __builtin_nontemporal_store(pack_m2(c3.m2, c3.i1), &tB[tbase + 48 + n16]);
      rmin = fminf(rmin, c3.m1);
    }
    c0 = Top2{3.4e38f, 3.4e38f, 0}; c1 = Top2{3.4e38f, 3.4e38f, 0};
    c2 = Top2{3.4e38f, 3.4e38f, 0}; c3 = Top2{3.4e38f, 3.4e38f, 0};
  }
  // one atomic per lane; order-preserving encoding (values can be negative!)
  atomicMin(&rowMinG[n0 + quad * 16 + n16], fenc(rmin));
}

// ======== rerank: per-code candidates | exact chains | epilogue ========
// (byte-identical to r7 - bit-exact outputs)
__global__ __launch_bounds__(256) void vq_rerank(
    const float* __restrict__ z, const float* __restrict__ cb,
    const float* __restrict__ Bk, const float* __restrict__ tA,
    const uint* __restrict__ tB, const uint* __restrict__ rowMinG,
    float* __restrict__ out, int* __restrict__ hist,
    float* __restrict__ loss_acc, u64* __restrict__ rowBest) {
  __shared__ float zt[MT][DD + 1];
  __shared__ float thr[MT];
  __shared__ float ArS[MT];
  __shared__ int wl[WCAP];
  __shared__ int wcnt;
  __shared__ int kwin[MT];
  __shared__ float lred[4];

  const int t = threadIdx.x;
  const int n0 = blockIdx.x * MT;
  const int bimg = n0 >> 10, hw0 = n0 & 1023;
  const float* zb = z + (size_t)bimg * DD * HW + hw0;

  if (t == 0) wcnt = 0;
  for (int li = t; li < MT * DD; li += 256) {
    int d = li >> 5, r = li & 31;
    zt[r][d] = zb[d * HW + r];
  }
  __syncthreads();

  const int w = t >> 6, lane = t & 63;

  if (t < MT) {
    thr[t] = fdec(rowMinG[n0 + t]) + MARGIN;
  } else if (t >= 128 && t < 192) {   // wave 2: Arow from zt, numpy-exact
    int rr = (t - 128) >> 1, half = t & 1;
    float h = np_pw128_sq(&zt[rr][half * 128]);
    float ho = __shfl_xor(h, 1);      // partner half (adjacent lane)
    if (half == 0) ArS[rr] = __fadd_rn(h, ho);   // h[0] + h[1], order kept
  }
  __syncthreads();

  auto exact_one = [&](int rr, int code) {   // numpy-exact ascending-d chain
    const float* cp = cb + (size_t)code * DD;
    float dot = 0.f;
#pragma unroll
    for (int d0 = 0; d0 < DD; d0 += 4) {
      float4 v = *(const float4*)(cp + d0);
      dot = fmaf(zt[rr][d0 + 0], v.x, dot);
      dot = fmaf(zt[rr][d0 + 1], v.y, dot);
      dot = fmaf(zt[rr][d0 + 2], v.z, dot);
      dot = fmaf(zt[rr][d0 + 3], v.w, dot);
    }
    float bd = __fsub_rn(__fadd_rn(ArS[rr], Bk[code]), __fmul_rn(2.f, dot));
    atomicMin(&rowBest[n0 + rr],
              ((u64)__float_as_uint(bd) << 32) | (unsigned)code);
  };

  // candidate scan: coalesced float4 over 4 consecutive rows of one tile.
  // tile argmin if min<=thr<min2; full 32 codes if min2<=thr (same logic).
  for (int it = 0; it < 8; ++it) {
    const int li = it * 256 + t;          // 0..2047
    const int tile = li >> 3, r4 = (li & 7) << 2;
    const f32x4 a4 = __builtin_nontemporal_load(
        (const f32x4*)&tA[(size_t)tile * NROWS + n0 + r4]);
#pragma unroll
    for (int e = 0; e < 4; ++e) {
      const int rr = r4 + e;
      const float th = thr[rr];
      if (a4[e] <= th) {
        const uint pk = __builtin_nontemporal_load(
            &tB[(size_t)tile * NROWS + n0 + rr]);
        const float m2f = __uint_as_float(pk & 0xFFFF0000u);
        if (m2f <= th) {               // rare: in-tile near-tie -> full tile
          for (int c = 0; c < 32; ++c) {
            int pos = atomicAdd(&wcnt, 1);
            if (pos < WCAP) wl[pos] = (rr << 16) | (tile * 32 + c);
            else exact_one(rr, tile * 32 + c);
          }
        } else {
          int pos = atomicAdd(&wcnt, 1);
          if (pos < WCAP) wl[pos] = (rr << 16) | (tile * 32 + (int)(pk & 31u));
          else exact_one(rr, tile * 32 + (int)(pk & 31u));
        }
      }
    }
  }
  __syncthreads();

  const int cnt = min(wcnt, WCAP);
  for (int e = t; e < cnt; e += 256) {
    const int ent = wl[e];
    exact_one(ent >> 16, ent & 0xFFFF);
  }
  __syncthreads();

  // ---- epilogue: indices + hist + z_q_st + loss (zt resident) ----
  if (t < MT) {
    u64 key = atomicMin(&rowBest[n0 + t], 0xFFFFFFFFFFFFFFFFull);  // read
    int bi = (int)(key & 0xFFFFFFFFull);
    kwin[t] = bi;
    atomicAdd(&hist[bi], 1);
    out[(size_t)NELEM + 1 + n0 + t] = (float)bi;
  }
  __syncthreads();

  float lsum = 0.f;
  for (int it = 0; it < MT * DD / 256; ++it) {
    int li = it * 256 + t;
    int d = li >> 5, rr = li & 31;
    float ze = zt[rr][d];
    float zq = cb[(size_t)kwin[rr] * DD + d];
    float diff = __fsub_rn(zq, ze);
    float st = __fadd_rn(ze, diff);        // z_e + (z_q - z_e)
    out[(size_t)(bimg * DD + d) * HW + hw0 + rr] = st;
    lsum = fmaf(diff, diff, lsum);
  }
#pragma unroll
  for (int off = 32; off > 0; off >>= 1) lsum += __shfl_down(lsum, off);
  if (lane == 0) lred[w] = lsum;
  __syncthreads();
  if (t == 0)
    atomicAdd(loss_acc, ((lred[0] + lred[1]) + (lred[2] + lred[3])));
}

// ---------------- finalize: vq_loss + perplexity ----------------
__global__ __launch_bounds__(256) void vq_final(const int* __restrict__ hist,
                                                const float* __restrict__ loss,
                                                float* __restrict__ out) {
  __shared__ float sred[256];
  int t = threadIdx.x;
  float s = 0.f;
  for (int k = t; k < KK; k += 256) {
    float p = (float)hist[k] * (1.f / 16384.f);
    s += p * logf(p + 1e-10f);
  }
  sred[t] = s;
  __syncthreads();
  for (int off = 128; off > 0; off >>= 1) {
    if (t < off) sred[t] += sred[t + off];
    __syncthreads();
  }
  if (t == 0) {
    float L = loss[0] / (float)NELEM;
    out[NELEM] = 1.25f * L;
    out[(size_t)NELEM + 1 + NROWS] = expf(-sred[0]);
  }
}

extern "C" void kernel_launch(void* const* d_in, const int* in_sizes, int n_in,
                              void* d_out, int out_size, void* d_ws, size_t ws_size,
                              hipStream_t stream) {
  const float* z = (const float*)d_in[0];   // (16,256,32,32) fp32
  const float* cb = (const float*)d_in[1];  // (8192,256) fp32
  float* out = (float*)d_out;               // fp32: [z_q_st | loss | idx | perp]

  float* wsf = (float*)d_ws;
  int* hist = (int*)d_ws;                          // 8192 ints
  float* loss = wsf + 8192;                        // 1 (+pad)
  int* ctr = (int*)(wsf + 8320);                   // 4 slice counters (zeroed)
  float* Bk = wsf + 8448;                          // 8192
  uint* rowMinG = (uint*)(wsf + 16640);            // 16384 u32
  u64* rowBest = (u64*)(wsf + 33024);              // 16384 u64 (128 KB)
  ushort* cbB = (ushort*)(wsf + 65792);            // 2.10M ushorts (4.2 MB)
  float* tA = wsf + 1114368;                       // 256*16384 f32 (16.8 MB)
  uint* tB = (uint*)(wsf + 5308672);               // 256*16384 u32 (16.8 MB)

  hipMemsetAsync(d_ws, 0, 8448 * sizeof(float), stream);
  hipMemsetAsync(wsf + 16640, 0xFF, 196608, stream);   // rowMinG + rowBest
  vq_prep<<<1056, 256, 0, stream>>>(cb, Bk, cbB);
  vq_screen<<<(NROWS / MS) * 4, 256, 0, stream>>>(z, cbB, Bk, tA, tB,
                                                  rowMinG, ctr);
  vq_rerank<<<NROWS / MT, 256, 0, stream>>>(z, cb, Bk, tA, tB, rowMinG, out,
                                            hist, loss, rowBest);
  vq_final<<<1, 256, 0, stream>>>(hist, loss, out);
}

// Round 9
// 221.304 us; speedup vs baseline: 1.0563x; 1.0563x over previous
//
#include <hip/hip_runtime.h>

#define DD 256
#define KK 8192
#define HW 1024
#define NROWS 16384
#define NELEM 4194304
#define MT 32            // rerank row-tile (loss-order preserving: DO NOT CHANGE)
#define MS 64            // screen row-tile
#define MARGIN 6e-4f     // bf16-screen deterministic bound (r0-r4 verified)
#define WCAP 1024
#define NSLICE 4

typedef __attribute__((ext_vector_type(8))) short short8;
typedef __attribute__((ext_vector_type(4))) float f32x4;
typedef __attribute__((ext_vector_type(4))) unsigned int ux4;
typedef unsigned short ushort;
typedef unsigned int uint;
typedef unsigned long long u64;

// ---- exact replication of numpy pairwise_sum (n=256) over squares ----
__device__ __forceinline__ float np_pw128_sq(const float* p) {
  float r[8];
#pragma unroll
  for (int j = 0; j < 8; ++j) r[j] = __fmul_rn(p[j], p[j]);
  for (int i = 8; i < 128; i += 8) {
#pragma unroll
    for (int j = 0; j < 8; ++j)
      r[j] = __fadd_rn(r[j], __fmul_rn(p[i + j], p[i + j]));
  }
  return __fadd_rn(__fadd_rn(__fadd_rn(r[0], r[1]), __fadd_rn(r[2], r[3])),
                   __fadd_rn(__fadd_rn(r[4], r[5]), __fadd_rn(r[6], r[7])));
}

__device__ __forceinline__ ushort f2bf(float x) {   // RNE float->bf16 bits
  uint u = __float_as_uint(x);
  u += 0x7FFF + ((u >> 16) & 1);
  return (ushort)(u >> 16);
}

// order-preserving float<->uint (screened minima are NEGATIVE - r5 lesson)
__device__ __forceinline__ uint fenc(float f) {
  uint u = __float_as_uint(f);
  return (u & 0x80000000u) ? ~u : (u | 0x80000000u);
}
__device__ __forceinline__ float fdec(uint k) {
  return __uint_as_float((k & 0x80000000u) ? (k & 0x7FFFFFFFu) : ~k);
}

// running top-2 (min, argmin, min2) helpers for the screen
struct Top2 { float m1, m2; int i1; };

__device__ __forceinline__ void top2_upd(Top2& s, const f32x4 a,
                                         const f32x4 Bs, int ibase) {
  float d0 = fmaf(-2.f, a[0], Bs[0]);
  float d1 = fmaf(-2.f, a[1], Bs[1]);
  float d2 = fmaf(-2.f, a[2], Bs[2]);
  float d3 = fmaf(-2.f, a[3], Bs[3]);
  float lo01 = fminf(d0, d1), hi01 = fmaxf(d0, d1);
  int io01 = d1 < d0 ? ibase + 1 : ibase;
  float lo23 = fminf(d2, d3), hi23 = fmaxf(d2, d3);
  int io23 = d3 < d2 ? ibase + 3 : ibase + 2;
  float n1 = fminf(lo01, lo23);
  int ni = lo23 < lo01 ? io23 : io01;
  float n2 = fminf(fmaxf(lo01, lo23), fminf(hi01, hi23));
  s.m2 = fminf(fmaxf(s.m1, n1), fminf(s.m2, n2));   // uses OLD m1
  s.i1 = n1 < s.m1 ? ni : s.i1;
  s.m1 = fminf(s.m1, n1);
}

__device__ __forceinline__ void top2_bfly(Top2& s, int off) {
  float om1 = __shfl_xor(s.m1, off);
  int oi1 = __shfl_xor(s.i1, off);
  float om2 = __shfl_xor(s.m2, off);
  s.m2 = fminf(fmaxf(s.m1, om1), fminf(s.m2, om2));
  s.i1 = om1 < s.m1 ? oi1 : s.i1;   // ties keep own; covered by m2<=thr path
  s.m1 = fminf(s.m1, om1);
}

__device__ __forceinline__ uint pack_m2(float m2, int i1) {
  // bf16 rounded toward -inf (conservative: never hides a full-scan), idx in low bits
  uint u = __float_as_uint(m2);
  uint hi = u & 0xFFFF0000u;
  if ((u & 0x80000000u) && (u & 0xFFFFu)) hi += 0x10000u;
  return hi | (uint)i1;
}

// ======== prep: Bk (2 threads/row, bit-exact) | cbB bf16 fragments ========
__global__ __launch_bounds__(256) void vq_prep(const float* __restrict__ cb,
                                               float* __restrict__ Bk,
                                               ushort* __restrict__ cbB) {
  const int b = blockIdx.x, t = threadIdx.x;
  if (b < 64) {                // ||e_k||^2, numpy-exact: half per thread
    int tid2 = b * 256 + t;
    int k = tid2 >> 1, half = tid2 & 1;
    float h = np_pw128_sq(cb + (size_t)k * DD + half * 128);
    float ho = __shfl_xor(h, 1);          // partner half (adjacent lane)
    if (half == 0) Bk[k] = __fadd_rn(h, ho);   // np(p) + np(p+128), order kept
  } else {                     // cbB fragments (layout verified r7/r8/r9)
    int tid = (b - 64) * 256 + t;
    int g = tid >> 9, s = (tid >> 6) & 7, lane = tid & 63;
    int code = g * 16 + (lane & 15);
    int dbase = s * 32 + (lane >> 4) * 8;
    const float* p = cb + (size_t)code * DD + dbase;
    ushort bb[8];
#pragma unroll
    for (int j = 0; j < 8; ++j) bb[j] = f2bf(p[j]);
    uint4 pk;
    pk.x = bb[0] | ((uint)bb[1] << 16);
    pk.y = bb[2] | ((uint)bb[3] << 16);
    pk.z = bb[4] | ((uint)bb[5] << 16);
    pk.w = bb[6] | ((uint)bb[7] << 16);
    *(uint4*)(cbB + (size_t)tid * 8) = pk;
  }
}

// ======== screen: bf16 MFMA, 64 rows/block, per-tile32 top-2 ========
// KEY FIX vs r6-r8: architectural VGPR demand is ~230 (aF alone = 128) but
// the compiler allocated 120-128 (the 4-wave/SIMD boundary), meaning the
// loop-invariant aF fragments were REMATERIALIZED (re-read from LDS) inside
// every gg iteration - hidden ds_read+lgkm stalls that explain the
// structure-invariant ~95us wall across 5 variants. Fix: (1) launch_bounds
// min-waves=1 lifts the VGPR cap to 512; (2) asm-opacify aF after extraction
// so its SSA origin is the asm, making rematerialization impossible.
// Numerics untouched -> tA/tB bit-identical.
#define GG_BODY(BUF, GGI, IB)                                                  \
  {                                                                            \
    f32x4 A0 = {0,0,0,0}, A1 = {0,0,0,0}, A2 = {0,0,0,0}, A3 = {0,0,0,0};      \
    _Pragma("unroll")                                                          \
    for (int s = 0; s < 8; ++s) {                                              \
      A0 = __builtin_amdgcn_mfma_f32_16x16x32_bf16(BUF[s], aF0[s], A0, 0, 0, 0);\
      A1 = __builtin_amdgcn_mfma_f32_16x16x32_bf16(BUF[s], aF1[s], A1, 0, 0, 0);\
      A2 = __builtin_amdgcn_mfma_f32_16x16x32_bf16(BUF[s], aF2[s], A2, 0, 0, 0);\
      A3 = __builtin_amdgcn_mfma_f32_16x16x32_bf16(BUF[s], aF3[s], A3, 0, 0, 0);\
    }                                                                          \
    const f32x4 Bs = *(const f32x4*)(BkS + (GGI) * 16 - cbase + quad * 4);     \
    top2_upd(c0, A0, Bs, IB); top2_upd(c1, A1, Bs, IB);                        \
    top2_upd(c2, A2, Bs, IB); top2_upd(c3, A3, Bs, IB);                        \
  }

__global__ __launch_bounds__(256, 1) void vq_screen(
    const float* __restrict__ z, const ushort* __restrict__ cbB,
    const float* __restrict__ Bk, float* __restrict__ tA,
    uint* __restrict__ tB, uint* __restrict__ rowMinG) {
  __shared__ ushort ztB[MS][264];   // 33 KB; 264 keeps 16B row alignment
  __shared__ float BkS[2048];       // this block's code-slice norms (8 KB)
  const int bid = blockIdx.x;
  const int rt = bid >> 2, cs = bid & 3;
  const int t = threadIdx.x;
  const int n0 = rt * MS;
  const int bimg = n0 >> 10, hw0 = n0 & 1023;
  const float* zb = z + (size_t)bimg * DD * HW + hw0;

  for (int li = t; li < MS * 128; li += 256) {   // 64 rows x 128 d-pairs
    int r = li & 63, dp = li >> 6;
    float v0 = zb[(size_t)(2 * dp) * HW + r];
    float v1 = zb[(size_t)(2 * dp + 1) * HW + r];
    *(uint*)&ztB[r][2 * dp] = (uint)f2bf(v0) | ((uint)f2bf(v1) << 16);
  }
  for (int li = t; li < 2048; li += 256) BkS[li] = Bk[cs * 2048 + li];
  __syncthreads();

  const int w = t >> 6, lane = t & 63;
  const int quad = lane >> 4, n16 = lane & 15;

  short8 aF0[8], aF1[8], aF2[8], aF3[8];   // z fragments, 4 row-groups
#pragma unroll
  for (int s = 0; s < 8; ++s) {
    aF0[s] = *(const short8*)&ztB[n16][s * 32 + quad * 8];
    aF1[s] = *(const short8*)&ztB[16 + n16][s * 32 + quad * 8];
    aF2[s] = *(const short8*)&ztB[32 + n16][s * 32 + quad * 8];
    aF3[s] = *(const short8*)&ztB[48 + n16][s * 32 + quad * 8];
  }
  // opacify: force aF into live VGPRs; compiler can no longer re-read LDS
#pragma unroll
  for (int s = 0; s < 8; ++s) {
    asm volatile("" : "+v"(*(ux4*)&aF0[s]));
    asm volatile("" : "+v"(*(ux4*)&aF1[s]));
    asm volatile("" : "+v"(*(ux4*)&aF2[s]));
    asm volatile("" : "+v"(*(ux4*)&aF3[s]));
  }

  const int gg0 = cs * 128 + w * 32;   // 32 16-code groups = 16 tiles per wave
  const int cbase = cs * 2048;
  Top2 c0 = {3.4e38f, 3.4e38f, 0}, c1 = {3.4e38f, 3.4e38f, 0};
  Top2 c2 = {3.4e38f, 3.4e38f, 0}, c3 = {3.4e38f, 3.4e38f, 0};
  float rmin = 3.4e38f;

  short8 b0[8], b1[8];
  {
    const ushort* bp = cbB + (size_t)gg0 * 4096 + lane * 8;
#pragma unroll
    for (int s = 0; s < 8; ++s) b0[s] = *(const short8*)(bp + s * 512);
  }

  for (int gp = 0; gp < 16; ++gp) {     // ping-pong pairs; tile = gg pair
    const int gg = gg0 + gp * 2;
    {
      const ushort* bp = cbB + (size_t)(gg + 1) * 4096 + lane * 8;
#pragma unroll
      for (int s = 0; s < 8; ++s) b1[s] = *(const short8*)(bp + s * 512);
    }
    GG_BODY(b0, gg, quad * 4)
    if (gp < 15) {
      const ushort* bp = cbB + (size_t)(gg + 2) * 4096 + lane * 8;
#pragma unroll
      for (int s = 0; s < 8; ++s) b0[s] = *(const short8*)(bp + s * 512);
    }
    GG_BODY(b1, gg + 1, 16 + quad * 4)
    // tile complete: merge quads, NT-store, track row-min, reset
    top2_bfly(c0, 16); top2_bfly(c0, 32);
    top2_bfly(c1, 16); top2_bfly(c1, 32);
    top2_bfly(c2, 16); top2_bfly(c2, 32);
    top2_bfly(c3, 16); top2_bfly(c3, 32);
    const size_t tbase = (size_t)(gg >> 1) * NROWS + n0;
    if (quad == 0) {
      __builtin_nontemporal_store(c0.m1, &tA[tbase + n16]);
      __builtin_nontemporal_store(pack_m2(c0.m2, c0.i1), &tB[tbase + n16]);
      rmin = fminf(rmin, c0.m1);
    } else if (quad == 1) {
      __builtin_nontemporal_store(c1.m1, &tA[tbase + 16 + n16]);
      __builtin_nontemporal_store(pack_m2(c1.m2, c1.i1), &tB[tbase + 16 + n16]);
      rmin = fminf(rmin, c1.m1);
    } else if (quad == 2) {
      __builtin_nontemporal_store(c2.m1, &tA[tbase + 32 + n16]);
      __builtin_nontemporal_store(pack_m2(c2.m2, c2.i1), &tB[tbase + 32 + n16]);
      rmin = fminf(rmin, c2.m1);
    } else {
      __builtin_nontemporal_store(c3.m1, &tA[tbase + 48 + n16]);
      __builtin_nontemporal_store(pack_m2(c3.m2, c3.i1), &tB[tbase + 48 + n16]);
      rmin = fminf(rmin, c3.m1);
    }
    c0 = Top2{3.4e38f, 3.4e38f, 0}; c1 = Top2{3.4e38f, 3.4e38f, 0};
    c2 = Top2{3.4e38f, 3.4e38f, 0}; c3 = Top2{3.4e38f, 3.4e38f, 0};
  }
  // one atomic per lane; order-preserving encoding (values can be negative!)
  atomicMin(&rowMinG[n0 + quad * 16 + n16], fenc(rmin));
}

// ======== rerank: per-code candidates | exact chains | epilogue ========
// (byte-identical to r7 - bit-exact outputs)
__global__ __launch_bounds__(256) void vq_rerank(
    const float* __restrict__ z, const float* __restrict__ cb,
    const float* __restrict__ Bk, const float* __restrict__ tA,
    const uint* __restrict__ tB, const uint* __restrict__ rowMinG,
    float* __restrict__ out, int* __restrict__ hist,
    float* __restrict__ loss_acc, u64* __restrict__ rowBest) {
  __shared__ float zt[MT][DD + 1];
  __shared__ float thr[MT];
  __shared__ float ArS[MT];
  __shared__ int wl[WCAP];
  __shared__ int wcnt;
  __shared__ int kwin[MT];
  __shared__ float lred[4];

  const int t = threadIdx.x;
  const int n0 = blockIdx.x * MT;
  const int bimg = n0 >> 10, hw0 = n0 & 1023;
  const float* zb = z + (size_t)bimg * DD * HW + hw0;

  if (t == 0) wcnt = 0;
  for (int li = t; li < MT * DD; li += 256) {
    int d = li >> 5, r = li & 31;
    zt[r][d] = zb[d * HW + r];
  }
  __syncthreads();

  const int w = t >> 6, lane = t & 63;

  if (t < MT) {
    thr[t] = fdec(rowMinG[n0 + t]) + MARGIN;
  } else if (t >= 128 && t < 192) {   // wave 2: Arow from zt, numpy-exact
    int rr = (t - 128) >> 1, half = t & 1;
    float h = np_pw128_sq(&zt[rr][half * 128]);
    float ho = __shfl_xor(h, 1);      // partner half (adjacent lane)
    if (half == 0) ArS[rr] = __fadd_rn(h, ho);   // h[0] + h[1], order kept
  }
  __syncthreads();

  auto exact_one = [&](int rr, int code) {   // numpy-exact ascending-d chain
    const float* cp = cb + (size_t)code * DD;
    float dot = 0.f;
#pragma unroll
    for (int d0 = 0; d0 < DD; d0 += 4) {
      float4 v = *(const float4*)(cp + d0);
      dot = fmaf(zt[rr][d0 + 0], v.x, dot);
      dot = fmaf(zt[rr][d0 + 1], v.y, dot);
      dot = fmaf(zt[rr][d0 + 2], v.z, dot);
      dot = fmaf(zt[rr][d0 + 3], v.w, dot);
    }
    float bd = __fsub_rn(__fadd_rn(ArS[rr], Bk[code]), __fmul_rn(2.f, dot));
    atomicMin(&rowBest[n0 + rr],
              ((u64)__float_as_uint(bd) << 32) | (unsigned)code);
  };

  // candidate scan: coalesced float4 over 4 consecutive rows of one tile.
  // tile argmin if min<=thr<min2; full 32 codes if min2<=thr (same logic).
  for (int it = 0; it < 8; ++it) {
    const int li = it * 256 + t;          // 0..2047
    const int tile = li >> 3, r4 = (li & 7) << 2;
    const f32x4 a4 = __builtin_nontemporal_load(
        (const f32x4*)&tA[(size_t)tile * NROWS + n0 + r4]);
#pragma unroll
    for (int e = 0; e < 4; ++e) {
      const int rr = r4 + e;
      const float th = thr[rr];
      if (a4[e] <= th) {
        const uint pk = __builtin_nontemporal_load(
            &tB[(size_t)tile * NROWS + n0 + rr]);
        const float m2f = __uint_as_float(pk & 0xFFFF0000u);
        if (m2f <= th) {               // rare: in-tile near-tie -> full tile
          for (int c = 0; c < 32; ++c) {
            int pos = atomicAdd(&wcnt, 1);
            if (pos < WCAP) wl[pos] = (rr << 16) | (tile * 32 + c);
            else exact_one(rr, tile * 32 + c);
          }
        } else {
          int pos = atomicAdd(&wcnt, 1);
          if (pos < WCAP) wl[pos] = (rr << 16) | (tile * 32 + (int)(pk & 31u));
          else exact_one(rr, tile * 32 + (int)(pk & 31u));
        }
      }
    }
  }
  __syncthreads();

  const int cnt = min(wcnt, WCAP);
  for (int e = t; e < cnt; e += 256) {
    const int ent = wl[e];
    exact_one(ent >> 16, ent & 0xFFFF);
  }
  __syncthreads();

  // ---- epilogue: indices + hist + z_q_st + loss (zt resident) ----
  if (t < MT) {
    u64 key = atomicMin(&rowBest[n0 + t], 0xFFFFFFFFFFFFFFFFull);  // read
    int bi = (int)(key & 0xFFFFFFFFull);
    kwin[t] = bi;
    atomicAdd(&hist[bi], 1);
    out[(size_t)NELEM + 1 + n0 + t] = (float)bi;
  }
  __syncthreads();

  float lsum = 0.f;
  for (int it = 0; it < MT * DD / 256; ++it) {
    int li = it * 256 + t;
    int d = li >> 5, rr = li & 31;
    float ze = zt[rr][d];
    float zq = cb[(size_t)kwin[rr] * DD + d];
    float diff = __fsub_rn(zq, ze);
    float st = __fadd_rn(ze, diff);        // z_e + (z_q - z_e)
    out[(size_t)(bimg * DD + d) * HW + hw0 + rr] = st;
    lsum = fmaf(diff, diff, lsum);
  }
#pragma unroll
  for (int off = 32; off > 0; off >>= 1) lsum += __shfl_down(lsum, off);
  if (lane == 0) lred[w] = lsum;
  __syncthreads();
  if (t == 0)
    atomicAdd(loss_acc, ((lred[0] + lred[1]) + (lred[2] + lred[3])));
}

// ---------------- finalize: vq_loss + perplexity ----------------
__global__ __launch_bounds__(256) void vq_final(const int* __restrict__ hist,
                                                const float* __restrict__ loss,
                                                float* __restrict__ out) {
  __shared__ float sred[256];
  int t = threadIdx.x;
  float s = 0.f;
  for (int k = t; k < KK; k += 256) {
    float p = (float)hist[k] * (1.f / 16384.f);
    s += p * logf(p + 1e-10f);
  }
  sred[t] = s;
  __syncthreads();
  for (int off = 128; off > 0; off >>= 1) {
    if (t < off) sred[t] += sred[t + off];
    __syncthreads();
  }
  if (t == 0) {
    float L = loss[0] / (float)NELEM;
    out[NELEM] = 1.25f * L;
    out[(size_t)NELEM + 1 + NROWS] = expf(-sred[0]);
  }
}

extern "C" void kernel_launch(void* const* d_in, const int* in_sizes, int n_in,
                              void* d_out, int out_size, void* d_ws, size_t ws_size,
                              hipStream_t stream) {
  const float* z = (const float*)d_in[0];   // (16,256,32,32) fp32
  const float* cb = (const float*)d_in[1];  // (8192,256) fp32
  float* out = (float*)d_out;               // fp32: [z_q_st | loss | idx | perp]

  float* wsf = (float*)d_ws;
  int* hist = (int*)d_ws;                          // 8192 ints
  float* loss = wsf + 8192;                        // 1 (+pad)
  float* Bk = wsf + 8448;                          // 8192
  uint* rowMinG = (uint*)(wsf + 16640);            // 16384 u32
  u64* rowBest = (u64*)(wsf + 33024);              // 16384 u64 (128 KB)
  ushort* cbB = (ushort*)(wsf + 65792);            // 2.10M ushorts (4.2 MB)
  float* tA = wsf + 1114368;                       // 256*16384 f32 (16.8 MB)
  uint* tB = (uint*)(wsf + 5308672);               // 256*16384 u32 (16.8 MB)

  hipMemsetAsync(d_ws, 0, 8448 * sizeof(float), stream);
  hipMemsetAsync(wsf + 16640, 0xFF, 196608, stream);   // rowMinG + rowBest
  vq_prep<<<1088, 256, 0, stream>>>(cb, Bk, cbB);
  vq_screen<<<(NROWS / MS) * NSLICE, 256, 0, stream>>>(z, cbB, Bk, tA, tB,
                                                       rowMinG);
  vq_rerank<<<NROWS / MT, 256, 0, stream>>>(z, cb, Bk, tA, tB, rowMinG, out,
                                            hist, loss, rowBest);
  vq_final<<<1, 256, 0, stream>>>(hist, loss, out);
}